// Round 5
// baseline (237.779 us; speedup 1.0000x reference)
//
#include <hip/hip_runtime.h>
#include <math.h>

#define VOCAB 2048
#define TPB   256
#define RPB   4          // rows per block = waves per block (no __syncthreads anywhere)
#define EPT   32         // elements per lane (2048 / 64)
#define NCH   8          // float4 chunks per lane
#define NBINS 64
// 64 bins cover (m - v) in [0, 10.667); kept tokens provably have
// m - v <= ln(2048/0.05) = 10.62, so the top-p crossing is always inside.
#define BIN_SCALE 6.0f
#define BCAP  256        // per-wave candidate cap (boundary ~6, kept ~50; 5x+ margin)

typedef float vf4 __attribute__((ext_vector_type(4)));

__device__ __forceinline__ unsigned long long pack_key(float z, int idx) {
    unsigned zb = __float_as_uint(z);
    zb = (zb & 0x80000000u) ? ~zb : (zb | 0x80000000u);       // order-preserving map
    return ((unsigned long long)zb << 32) | (unsigned)(VOCAB - 1 - idx); // min-idx tiebreak
}

__global__ __launch_bounds__(TPB, 6) void sampler_kernel(
    const float* __restrict__ logits,
    const float* __restrict__ uni,
    float* __restrict__ out_idx,    // [B]
    float* __restrict__ out_probs)  // [B,V]
{
    const int wid  = threadIdx.x >> 6;
    const int lane = threadIdx.x & 63;
    const int row  = blockIdx.x * RPB + wid;

    // per-wave private LDS regions — produce/consume within one wave only
    __shared__ float s_bins[RPB][NBINS];
    __shared__ float s_cv[RPB][BCAP];   // phase A: boundary values; phase B: kept values
    __shared__ float s_ce[RPB][BCAP];   // phase A: boundary exps;   phase B: kept idx bits
    __shared__ int   s_cnt[RPB], s_cnt2[RPB];

    float* bins = s_bins[wid];
    float* cv   = s_cv[wid];
    float* ce   = s_ce[wid];

    const float* lrow = logits    + (size_t)row * VOCAB;
    const float* urow = uni       + (size_t)row * VOCAB;
    float*       prow = out_probs + (size_t)row * VOCAB;

    bins[lane] = 0.0f;                          // 64 lanes cover 64 bins
    if (lane == 0) { s_cnt[wid] = 0; s_cnt2[wid] = 0; }
    __builtin_amdgcn_wave_barrier();

    // ---- coalesced row load: 8 x float4 per lane, all in flight early ----
    vf4 a[NCH];
    #pragma unroll
    for (int c = 0; c < NCH; c++)
        a[c] = *(const vf4*)(lrow + c * 256 + lane * 4);

    float s[EPT];
    #pragma unroll
    for (int c = 0; c < NCH; c++) {
        s[4*c+0] = a[c].x * 1.25f; s[4*c+1] = a[c].y * 1.25f;
        s[4*c+2] = a[c].z * 1.25f; s[4*c+3] = a[c].w * 1.25f;
    }

    // ---- wave max (butterfly -> every lane holds m) ----
    float m = s[0];
    #pragma unroll
    for (int j = 1; j < EPT; j++) m = fmaxf(m, s[j]);
    #pragma unroll
    for (int off = 32; off; off >>= 1) m = fmaxf(m, __shfl_xor(m, off));

    // ---- exp pass: row sum (f32 lane, f64 cross-lane) + exp-mass histogram ----
    float psum = 0.0f;
    #pragma unroll
    for (int j = 0; j < EPT; j++) {
        float e = __expf(s[j] - m);
        psum += e;
        int b = (int)((m - s[j]) * BIN_SCALE);
        if (b < NBINS) atomicAdd(&bins[b], e);
    }
    double S = (double)psum;
    #pragma unroll
    for (int off = 32; off; off >>= 1) S += __shfl_xor(S, off);
    const double pS = 0.95 * S;
    __builtin_amdgcn_wave_barrier();            // same-wave DS in-order; pin compiler

    // ---- 64-bin prefix scan in-wave, find boundary bin ----
    const float bf = bins[lane];
    double c = (double)bf;
    #pragma unroll
    for (int d = 1; d < 64; d <<= 1) {
        double o = __shfl_up(c, d);
        if (lane >= d) c += o;
    }
    unsigned long long ball = __ballot(c > pS);
    const int    bstar     = ball ? (__ffsll(ball) - 1) : (NBINS - 1);
    const double cumBefore = __shfl(c - (double)bf, bstar);   // exclusive prefix

    // ---- compact boundary-bin candidates (cnt ~6) ----
    #pragma unroll
    for (int j = 0; j < EPT; j++) {
        int b = (int)((m - s[j]) * BIN_SCALE);
        if (b == bstar) {
            int pos = atomicAdd(&s_cnt[wid], 1);
            if (pos < BCAP) { cv[pos] = s[j]; ce[pos] = __expf(s[j] - m); }
        }
    }
    __builtin_amdgcn_wave_barrier();
    const int cnt = min(s_cnt[wid], BCAP);

    // ---- replicated O(cnt^2) boundary resolution -> SK (broadcast LDS reads) ----
    float SKb = 0.0f;
    for (int i = 0; i < cnt; i++) {
        float vi = cv[i], part = 0.0f;
        for (int jj = 0; jj < cnt; jj++)
            part += (cv[jj] > vi) ? ce[jj] : 0.0f;
        if (cumBefore + (double)part <= pS) SKb += ce[i];
    }
    const float invSK = 1.0f / (float)(cumBefore + (double)SKb);

    // ---- keep decision per element ----
    unsigned keptMask = 0;
    #pragma unroll
    for (int j = 0; j < EPT; j++) {
        int  b = (int)((m - s[j]) * BIN_SCALE);
        bool kept;
        if (b < bstar)      kept = true;
        else if (b > bstar) kept = false;
        else {
            float part = 0.0f;
            for (int i = 0; i < cnt; i++)
                part += (cv[i] > s[j]) ? ce[i] : 0.0f;
            kept = (cumBefore + (double)part) <= pS;
        }
        if (kept) keptMask |= (1u << j);
    }

    // ---- probs write (nontemporal, never re-read); cheap unconditional __expf ----
    #pragma unroll
    for (int cch = 0; cch < NCH; cch++) {
        vf4 p;
        p.x = ((keptMask >> (4*cch+0)) & 1u) ? __expf(s[4*cch+0] - m) * invSK : 0.0f;
        p.y = ((keptMask >> (4*cch+1)) & 1u) ? __expf(s[4*cch+1] - m) * invSK : 0.0f;
        p.z = ((keptMask >> (4*cch+2)) & 1u) ? __expf(s[4*cch+2] - m) * invSK : 0.0f;
        p.w = ((keptMask >> (4*cch+3)) & 1u) ? __expf(s[4*cch+3] - m) * invSK : 0.0f;
        __builtin_nontemporal_store(p, (vf4*)(prow + cch * 256 + lane * 4));
    }
    __builtin_amdgcn_wave_barrier();            // keep-loop reads of cv/ce done

    // ---- compact kept tokens (value, idx) — cv/ce reused ----
    unsigned long long key = 0ull;              // below any real packed key
    #pragma unroll
    for (int j = 0; j < EPT; j++) {
        if ((keptMask >> j) & 1u) {
            int idx = (j >> 2) * 256 + lane * 4 + (j & 3);
            int pos = atomicAdd(&s_cnt2[wid], 1);
            if (pos < BCAP) { cv[pos] = s[j]; ce[pos] = __int_as_float(idx); }
            else {                              // overflow fallback (never on this data)
                float z = s[j] + (-logf(-logf(urow[idx])));
                unsigned long long kk = pack_key(z, idx);
                key = (kk > key) ? kk : key;
            }
        }
    }
    __builtin_amdgcn_wave_barrier();
    const int k  = s_cnt2[wid];
    const int kl = min(k, BCAP);

    // ---- Gumbel-max over compacted kept list (ONE logf-pair execution per wave) ----
    for (int i = lane; i < kl; i += 64) {
        float sv  = cv[i];
        int   idx = __float_as_int(ce[i]);
        float z   = sv + (-logf(-logf(urow[idx])));   // sparse L3-resident gather
        unsigned long long kk = pack_key(z, idx);
        key = (kk > key) ? kk : key;
    }
    #pragma unroll
    for (int off = 32; off; off >>= 1) {
        unsigned long long ok = __shfl_xor(key, off);
        key = (ok > key) ? ok : key;
    }
    if (lane == 0)
        out_idx[row] = (float)(VOCAB - 1 - (int)(key & 0xFFFFFFFFu));
}

extern "C" void kernel_launch(void* const* d_in, const int* in_sizes, int n_in,
                              void* d_out, int out_size, void* d_ws, size_t ws_size,
                              hipStream_t stream) {
    const float* logits = (const float*)d_in[0];
    const float* u      = (const float*)d_in[1];
    const int B = in_sizes[0] / VOCAB;   // 8192
    float* out_idx   = (float*)d_out;          // sampled [B,1] flat, return order
    float* out_probs = (float*)d_out + B;      // probs [B,V]
    sampler_kernel<<<B / RPB, TPB, 0, stream>>>(logits, u, out_idx, out_probs);
}

// Round 6
// 194.330 us; speedup vs baseline: 1.2236x; 1.2236x over previous
//
#include <hip/hip_runtime.h>
#include <math.h>

#define VOCAB 2048
#define TPB   128        // 2 waves per block, ONE row per block (small barrier domain)
#define EPT   16         // elements per thread (2048 / 128) — fits registers, no spill (R5 lesson)
#define NCH   4          // float4 chunks per thread
#define NBINS 64
// 64 bins cover (m - v) in [0, 10.667); kept tokens provably have
// m - v <= ln(2048/0.05) = 10.62, so the top-p crossing is always inside.
#define BIN_SCALE 6.0f
#define BCAP  256        // boundary candidates (~6 expected) / kept tokens (~50 expected)

typedef float vf4 __attribute__((ext_vector_type(4)));

__device__ __forceinline__ unsigned long long pack_key(float z, int idx) {
    unsigned zb = __float_as_uint(z);
    zb = (zb & 0x80000000u) ? ~zb : (zb | 0x80000000u);       // order-preserving map
    return ((unsigned long long)zb << 32) | (unsigned)(VOCAB - 1 - idx); // min-idx tiebreak
}

__global__ __launch_bounds__(TPB, 8) void sampler_kernel(
    const float* __restrict__ logits,
    const float* __restrict__ uni,
    float* __restrict__ out_idx,    // [B]
    float* __restrict__ out_probs)  // [B,V]
{
    const int t    = threadIdx.x;
    const int lane = t & 63;
    const int wid  = t >> 6;        // 0 or 1
    const int row  = blockIdx.x;

    __shared__ float  s_bins[NBINS];
    __shared__ float  s_wf[2];
    __shared__ double s_wd[2];
    __shared__ unsigned long long s_key[2];
    __shared__ int    s_cnt, s_cnt2;
    __shared__ float  s_cv[BCAP];   // boundary values
    __shared__ float  s_ce[BCAP];   // boundary exps
    __shared__ float  s_kv[BCAP];   // kept values
    __shared__ int    s_ki[BCAP];   // kept indices

    const float* lrow = logits    + (size_t)row * VOCAB;
    const float* urow = uni       + (size_t)row * VOCAB;
    float*       prow = out_probs + (size_t)row * VOCAB;

    if (t < NBINS) s_bins[t] = 0.0f;
    if (t == 0) { s_cnt = 0; s_cnt2 = 0; }

    // ---- coalesced load: 4 x float4 per thread (16 floats), issued up front ----
    vf4 a[NCH];
    #pragma unroll
    for (int c = 0; c < NCH; c++)
        a[c] = *(const vf4*)(lrow + c * 512 + t * 4);

    float s[EPT];
    #pragma unroll
    for (int c = 0; c < NCH; c++) {
        s[4*c+0] = a[c].x * 1.25f; s[4*c+1] = a[c].y * 1.25f;
        s[4*c+2] = a[c].z * 1.25f; s[4*c+3] = a[c].w * 1.25f;
    }

    // ---- block max: wave butterfly + 2-entry LDS combine ----
    float lm = s[0];
    #pragma unroll
    for (int j = 1; j < EPT; j++) lm = fmaxf(lm, s[j]);
    #pragma unroll
    for (int off = 32; off; off >>= 1) lm = fmaxf(lm, __shfl_xor(lm, off));
    if (lane == 0) s_wf[wid] = lm;
    __syncthreads();                                    // B1 (covers LDS init)
    const float m = fmaxf(s_wf[0], s_wf[1]);

    // ---- exp pass (e NOT stored — recomputed later; protects VGPR budget) ----
    float psum = 0.0f;
    #pragma unroll
    for (int j = 0; j < EPT; j++) {
        float e = __expf(s[j] - m);
        psum += e;
        int b = (int)((m - s[j]) * BIN_SCALE);
        if (b < NBINS) atomicAdd(&s_bins[b], e);
    }
    double dp = (double)psum;
    #pragma unroll
    for (int off = 32; off; off >>= 1) dp += __shfl_xor(dp, off);
    if (lane == 0) s_wd[wid] = dp;
    __syncthreads();                                    // B2

    // ---- replicated (both waves) 64-bin f64 prefix scan -> boundary bin ----
    const double S  = s_wd[0] + s_wd[1];
    const double pS = 0.95 * S;
    const float  bf = s_bins[lane];
    double c = (double)bf;
    #pragma unroll
    for (int d = 1; d < 64; d <<= 1) {
        double o = __shfl_up(c, d);
        if (lane >= d) c += o;
    }
    unsigned long long ball = __ballot(c > pS);
    const int    bstar     = ball ? (__ffsll(ball) - 1) : (NBINS - 1);
    const double cumBefore = __shfl(c - (double)bf, bstar);   // exclusive prefix

    // ---- compact boundary-bin candidates (cnt ~6) ----
    #pragma unroll
    for (int j = 0; j < EPT; j++) {
        int b = (int)((m - s[j]) * BIN_SCALE);
        if (b == bstar) {
            int pos = atomicAdd(&s_cnt, 1);
            if (pos < BCAP) { s_cv[pos] = s[j]; s_ce[pos] = __expf(s[j] - m); }
        }
    }
    __syncthreads();                                    // B3
    const int cnt = min(s_cnt, BCAP);

    // ---- replicated O(cnt^2) boundary resolution -> SK (broadcast LDS reads) ----
    float SKb = 0.0f;
    for (int i = 0; i < cnt; i++) {
        float vi = s_cv[i], part = 0.0f;
        for (int jj = 0; jj < cnt; jj++)
            part += (s_cv[jj] > vi) ? s_ce[jj] : 0.0f;
        if (cumBefore + (double)part <= pS) SKb += s_ce[i];
    }
    const float invSK = 1.0f / (float)(cumBefore + (double)SKb);

    // ---- keep decisions ----
    unsigned keptMask = 0;
    #pragma unroll
    for (int j = 0; j < EPT; j++) {
        int  b = (int)((m - s[j]) * BIN_SCALE);
        bool kept;
        if (b < bstar)      kept = true;
        else if (b > bstar) kept = false;
        else {
            float part = 0.0f;
            for (int i = 0; i < cnt; i++)
                part += (s_cv[i] > s[j]) ? s_ce[i] : 0.0f;
            kept = (cumBefore + (double)part) <= pS;
        }
        if (kept) keptMask |= (1u << j);
    }

    // ---- probs write (nontemporal; __expf recomputed — cheap) ----
    #pragma unroll
    for (int cch = 0; cch < NCH; cch++) {
        vf4 p;
        p.x = ((keptMask >> (4*cch+0)) & 1u) ? __expf(s[4*cch+0] - m) * invSK : 0.0f;
        p.y = ((keptMask >> (4*cch+1)) & 1u) ? __expf(s[4*cch+1] - m) * invSK : 0.0f;
        p.z = ((keptMask >> (4*cch+2)) & 1u) ? __expf(s[4*cch+2] - m) * invSK : 0.0f;
        p.w = ((keptMask >> (4*cch+3)) & 1u) ? __expf(s[4*cch+3] - m) * invSK : 0.0f;
        __builtin_nontemporal_store(p, (vf4*)(prow + cch * 512 + t * 4));
    }

    // ---- compact kept tokens (separate arrays: no extra barrier vs s_cv reuse) ----
    unsigned long long key = 0ull;
    #pragma unroll
    for (int j = 0; j < EPT; j++) {
        if ((keptMask >> j) & 1u) {
            int idx = (j >> 2) * 512 + t * 4 + (j & 3);
            int pos = atomicAdd(&s_cnt2, 1);
            if (pos < BCAP) { s_kv[pos] = s[j]; s_ki[pos] = idx; }
            else {          // overflow fallback (never on this data) — correctness only
                float z = s[j] + (-logf(-logf(urow[idx])));
                unsigned long long kk = pack_key(z, idx);
                key = (kk > key) ? kk : key;
            }
        }
    }
    __syncthreads();                                    // B4
    const int k  = s_cnt2;
    const int kl = min(k, BCAP);

    // ---- Gumbel-max over compacted kept list (kl~50 -> ONE logf-pair, wave0 only) ----
    for (int i = t; i < kl; i += TPB) {
        float z = s_kv[i] + (-logf(-logf(urow[s_ki[i]])));   // sparse L3 gather, lib logf
        unsigned long long kk = pack_key(z, s_ki[i]);
        key = (kk > key) ? kk : key;
    }
    #pragma unroll
    for (int off = 32; off; off >>= 1) {
        unsigned long long ok = __shfl_xor(key, off);
        key = (ok > key) ? ok : key;
    }
    if (lane == 0) s_key[wid] = key;
    __syncthreads();                                    // B5
    if (t == 0) {
        unsigned long long k0 = (s_key[0] > s_key[1]) ? s_key[0] : s_key[1];
        out_idx[row] = (float)(VOCAB - 1 - (int)(k0 & 0xFFFFFFFFu));
    }
}

extern "C" void kernel_launch(void* const* d_in, const int* in_sizes, int n_in,
                              void* d_out, int out_size, void* d_ws, size_t ws_size,
                              hipStream_t stream) {
    const float* logits = (const float*)d_in[0];
    const float* u      = (const float*)d_in[1];
    const int B = in_sizes[0] / VOCAB;   // 8192
    float* out_idx   = (float*)d_out;          // sampled [B,1] flat, return order
    float* out_probs = (float*)d_out + B;      // probs [B,V]
    sampler_kernel<<<B, TPB, 0, stream>>>(logits, u, out_idx, out_probs);
}

// Round 7
// 185.333 us; speedup vs baseline: 1.2830x; 1.0485x over previous
//
#include <hip/hip_runtime.h>
#include <math.h>

#define VOCAB 2048
#define TPB   256        // 4 waves, ONE row at a time (R2's byte-minimal config)
#define ROWS  4          // rows per block, software-pipelined loads
#define NBINS 64
// 64 bins cover (m - v) in [0, 10.667); kept tokens provably have
// m - v <= ln(2048/0.05) = 10.62, so the top-p crossing is always inside.
#define BIN_SCALE 6.0f
#define BCAP  256        // boundary candidates (~6) / kept tokens (~50)

typedef float vf4 __attribute__((ext_vector_type(4)));

__device__ __forceinline__ unsigned long long pack_key(float z, int idx) {
    unsigned zb = __float_as_uint(z);
    zb = (zb & 0x80000000u) ? ~zb : (zb | 0x80000000u);       // order-preserving map
    return ((unsigned long long)zb << 32) | (unsigned)(VOCAB - 1 - idx); // min-idx tiebreak
}

__global__ __launch_bounds__(TPB, 8) void sampler_kernel(
    const float* __restrict__ logits,
    const float* __restrict__ uni,
    float* __restrict__ out_idx,    // [B]
    float* __restrict__ out_probs)  // [B,V]
{
    const int t    = threadIdx.x;
    const int lane = t & 63;
    const int wid  = t >> 6;
    const int row0 = blockIdx.x * ROWS;

    __shared__ float  s_bins[ROWS][NBINS];  // per-row histograms (no reset races)
    __shared__ float  s_wf[4];
    __shared__ double s_wd[4];
    __shared__ unsigned long long s_key[4]; // slow path only
    __shared__ int    s_cnt[ROWS], s_cnt2[ROWS];
    __shared__ float  s_cv[BCAP];           // boundary values
    __shared__ float  s_ce[BCAP];           // boundary exps
    __shared__ float  s_kv[BCAP];           // kept values
    __shared__ int    s_ki[BCAP];           // kept indices

    ((float*)s_bins)[t] = 0.0f;             // ROWS*NBINS == 256 == TPB
    if (t < ROWS) { s_cnt[t] = 0; s_cnt2[t] = 0; }

    // ---- prime the pipeline: row 0 loads in flight ----
    vf4 c0 = *(const vf4*)(logits + (size_t)row0 * VOCAB + t * 4);
    vf4 c1 = *(const vf4*)(logits + (size_t)row0 * VOCAB + VOCAB / 2 + t * 4);

    #pragma unroll
    for (int r = 0; r < ROWS; r++) {
        const int    row  = row0 + r;
        const float* urow = uni       + (size_t)row * VOCAB;
        float*       prow = out_probs + (size_t)row * VOCAB;

        // ---- issue NEXT row's loads before touching this row (latency hiding) ----
        vf4 n0, n1;
        if (r + 1 < ROWS) {
            n0 = *(const vf4*)(logits + (size_t)(row + 1) * VOCAB + t * 4);
            n1 = *(const vf4*)(logits + (size_t)(row + 1) * VOCAB + VOCAB / 2 + t * 4);
        }

        float s[8] = {c0.x * 1.25f, c0.y * 1.25f, c0.z * 1.25f, c0.w * 1.25f,
                      c1.x * 1.25f, c1.y * 1.25f, c1.z * 1.25f, c1.w * 1.25f};

        // ---- block max ----
        float lm = s[0];
        #pragma unroll
        for (int j = 1; j < 8; j++) lm = fmaxf(lm, s[j]);
        #pragma unroll
        for (int off = 32; off; off >>= 1) lm = fmaxf(lm, __shfl_xor(lm, off));
        if (lane == 0) s_wf[wid] = lm;
        __syncthreads();                                // B1 (r==0: covers LDS init)
        const float m = fmaxf(fmaxf(s_wf[0], s_wf[1]), fmaxf(s_wf[2], s_wf[3]));

        // ---- exp pass: f64 row-sum + exp-mass histogram (e transient: VGPR lean) ----
        float psum = 0.0f;
        #pragma unroll
        for (int j = 0; j < 8; j++) {
            float e = __expf(s[j] - m);
            psum += e;
            int b = (int)((m - s[j]) * BIN_SCALE);
            if (b < NBINS) atomicAdd(&s_bins[r][b], e);
        }
        double dp = (double)psum;
        #pragma unroll
        for (int off = 32; off; off >>= 1) dp += __shfl_xor(dp, off);
        if (lane == 0) s_wd[wid] = dp;
        __syncthreads();                                // B2

        // ---- replicated 64-bin f64 prefix scan -> boundary bin ----
        const double S  = s_wd[0] + s_wd[1] + s_wd[2] + s_wd[3];
        const double pS = 0.95 * S;
        const float  bf = s_bins[r][lane];
        double c = (double)bf;
        #pragma unroll
        for (int d = 1; d < 64; d <<= 1) {
            double o = __shfl_up(c, d);
            if (lane >= d) c += o;
        }
        unsigned long long ball = __ballot(c > pS);
        const int    bstar     = ball ? (__ffsll(ball) - 1) : (NBINS - 1);
        const double cumBefore = __shfl(c - (double)bf, bstar);

        // ---- compact boundary-bin candidates ----
        #pragma unroll
        for (int j = 0; j < 8; j++) {
            int b = (int)((m - s[j]) * BIN_SCALE);
            if (b == bstar) {
                int pos = atomicAdd(&s_cnt[r], 1);
                if (pos < BCAP) { s_cv[pos] = s[j]; s_ce[pos] = __expf(s[j] - m); }
            }
        }
        __syncthreads();                                // B3
        const int cnt = min(s_cnt[r], BCAP);

        // ---- replicated O(cnt^2) boundary resolution -> SK ----
        float SKb = 0.0f;
        for (int i = 0; i < cnt; i++) {
            float vi = s_cv[i], part = 0.0f;
            for (int jj = 0; jj < cnt; jj++)
                part += (s_cv[jj] > vi) ? s_ce[jj] : 0.0f;
            if (cumBefore + (double)part <= pS) SKb += s_ce[i];
        }
        const float invSK = 1.0f / (float)(cumBefore + (double)SKb);

        // ---- keep decisions ----
        unsigned keptMask = 0;
        #pragma unroll
        for (int j = 0; j < 8; j++) {
            int  b = (int)((m - s[j]) * BIN_SCALE);
            bool kept;
            if (b < bstar)      kept = true;
            else if (b > bstar) kept = false;
            else {
                float part = 0.0f;
                for (int i = 0; i < cnt; i++)
                    part += (s_cv[i] > s[j]) ? s_ce[i] : 0.0f;
                kept = (cumBefore + (double)part) <= pS;
            }
            if (kept) keptMask |= (1u << j);
        }

        // ---- probs write (nontemporal; __expf recomputed, 2 inst each) ----
        vf4 p0, p1;
        p0.x = (keptMask & 0x01) ? __expf(s[0] - m) * invSK : 0.0f;
        p0.y = (keptMask & 0x02) ? __expf(s[1] - m) * invSK : 0.0f;
        p0.z = (keptMask & 0x04) ? __expf(s[2] - m) * invSK : 0.0f;
        p0.w = (keptMask & 0x08) ? __expf(s[3] - m) * invSK : 0.0f;
        p1.x = (keptMask & 0x10) ? __expf(s[4] - m) * invSK : 0.0f;
        p1.y = (keptMask & 0x20) ? __expf(s[5] - m) * invSK : 0.0f;
        p1.z = (keptMask & 0x40) ? __expf(s[6] - m) * invSK : 0.0f;
        p1.w = (keptMask & 0x80) ? __expf(s[7] - m) * invSK : 0.0f;
        __builtin_nontemporal_store(p0, (vf4*)(prow + t * 4));
        __builtin_nontemporal_store(p1, (vf4*)(prow + VOCAB / 2 + t * 4));

        // ---- compact kept tokens ----
        unsigned long long ovKey = 0ull;
        #pragma unroll
        for (int j = 0; j < 8; j++) {
            if ((keptMask >> j) & 1u) {
                int idx = (j < 4) ? (t * 4 + j) : (VOCAB / 2 + t * 4 + (j - 4));
                int pos = atomicAdd(&s_cnt2[r], 1);
                if (pos < BCAP) { s_kv[pos] = s[j]; s_ki[pos] = idx; }
                else {          // never on this data; correctness fallback
                    float z = s[j] + (-logf(-logf(urow[idx])));
                    unsigned long long kk = pack_key(z, idx);
                    ovKey = (kk > ovKey) ? kk : ovKey;
                }
            }
        }
        __syncthreads();                                // B4
        const int k = s_cnt2[r];

        if (k <= BCAP) {
            // fast path: wave0 alone gathers+reduces+stores; waves 1-3 run ahead
            // into row r+1 (their next s_kv write is after B3(r+1) — race-free).
            if (wid == 0) {
                unsigned long long key = 0ull;
                for (int i = lane; i < k; i += 64) {
                    float z = s_kv[i] + (-logf(-logf(urow[s_ki[i]])));  // lib logf
                    unsigned long long kk = pack_key(z, s_ki[i]);
                    key = (kk > key) ? kk : key;
                }
                #pragma unroll
                for (int off = 32; off; off >>= 1) {
                    unsigned long long ok = __shfl_xor(key, off);
                    key = (ok > key) ? ok : key;
                }
                if (lane == 0)
                    out_idx[row] = (float)(VOCAB - 1 - (int)(key & 0xFFFFFFFFu));
            }
        } else {
            // overflow slow path (uniform branch): all waves + barrier
            unsigned long long key = ovKey;
            for (int i = t; i < BCAP; i += TPB) {
                float z = s_kv[i] + (-logf(-logf(urow[s_ki[i]])));
                unsigned long long kk = pack_key(z, s_ki[i]);
                key = (kk > key) ? kk : key;
            }
            #pragma unroll
            for (int off = 32; off; off >>= 1) {
                unsigned long long ok = __shfl_xor(key, off);
                key = (ok > key) ? ok : key;
            }
            if (lane == 0) s_key[wid] = key;
            __syncthreads();
            if (t == 0) {
                unsigned long long k0 = s_key[0];
                #pragma unroll
                for (int w = 1; w < 4; w++) k0 = (s_key[w] > k0) ? s_key[w] : k0;
                out_idx[row] = (float)(VOCAB - 1 - (int)(k0 & 0xFFFFFFFFu));
            }
        }

        c0 = n0; c1 = n1;
    }
}

extern "C" void kernel_launch(void* const* d_in, const int* in_sizes, int n_in,
                              void* d_out, int out_size, void* d_ws, size_t ws_size,
                              hipStream_t stream) {
    const float* logits = (const float*)d_in[0];
    const float* u      = (const float*)d_in[1];
    const int B = in_sizes[0] / VOCAB;   // 8192
    float* out_idx   = (float*)d_out;          // sampled [B,1] flat, return order
    float* out_probs = (float*)d_out + B;      // probs [B,V]
    sampler_kernel<<<B / ROWS, TPB, 0, stream>>>(logits, u, out_idx, out_probs);
}